// Round 1
// baseline (27365.149 us; speedup 1.0000x reference)
//
#include <hip/hip_runtime.h>

#define SEQn   1024
#define BATCHn 64
#define EMBn   256
#define HIDn   512
#define VOCn   512

#define NL1 64
#define NL2 128
#define NFC 16
#define NBLK (NL1 + NL2 + NFC)   /* 208 blocks, <= 256 CUs -> all co-resident */
#define NPHASE (SEQn + 2)        /* 1026 phases: skewed L1 / L2 / FC pipeline */

using f16   = _Float16;
using half8 = __attribute__((ext_vector_type(8))) _Float16;
using f32x4 = __attribute__((ext_vector_type(4))) float;

/* workspace layout (bytes) */
#define WS_FLAGS 0                                /* 256 ints              */
#define WS_H1    4096                             /* 2 x [64][512] f16     */
#define WS_H2    (WS_H1 + 2*BATCHn*HIDn*2)
#define WS_P1    (WS_H2 + 2*BATCHn*HIDn*2)        /* [512][2048] f16, 2MB  */

__device__ __forceinline__ float sigm_(float v) { return 1.0f / (1.0f + __expf(-v)); }
__device__ __forceinline__ float tanh_(float v) { return 1.0f - 2.0f / (__expf(2.0f * v) + 1.0f); }

/* ---- init: zero barrier flags, seed h1/h2 ping-pong buffer 0 from h0 ---- */
__global__ void k_init(const float* __restrict__ h0, char* __restrict__ ws) {
  int i = blockIdx.x * 256 + threadIdx.x;          /* grid 128*256 = 32768 */
  f16* h1b = (f16*)(ws + WS_H1);
  f16* h2b = (f16*)(ws + WS_H2);
  float v = h0[i];
  h1b[i] = (f16)v;
  h2b[i] = (f16)v;
  if (i < 1024) ((int*)(ws + WS_FLAGS))[i] = 0;
}

/* ---- P1[v][g] = sum_e emb[v][e]*Wih1[g][e] + bih1[g] + bhh1[g] (fp16) ---- */
__global__ void k_p1(const float* __restrict__ emb, const float* __restrict__ Wih1,
                     const float* __restrict__ bih1, const float* __restrict__ bhh1,
                     char* __restrict__ ws) {
  __shared__ float elds[32 * 256];
  int tid = threadIdx.x;
  int vb = blockIdx.x >> 5, gb = blockIdx.x & 31;  /* grid 512 */
  for (int i = tid; i < 32 * 256; i += 256) elds[i] = emb[vb * 32 * 256 + i];
  __syncthreads();
  int gl = tid & 63, vs = tid >> 6;
  int g = gb * 64 + gl;
  float bias = bih1[g] + bhh1[g];
  float acc[8];
#pragma unroll
  for (int r = 0; r < 8; ++r) acc[r] = bias;
  const float* wrow = Wih1 + g * EMBn;
#pragma unroll 4
  for (int e = 0; e < EMBn; ++e) {
    float w = wrow[e];
#pragma unroll
    for (int r = 0; r < 8; ++r) acc[r] += elds[(vs * 8 + r) * 256 + e] * w;
  }
  f16* P1 = (f16*)(ws + WS_P1);
#pragma unroll
  for (int r = 0; r < 8; ++r) P1[(vb * 32 + vs * 8 + r) * 2048 + g] = (f16)acc[r];
}

/* ---- persistent skewed-pipeline kernel ---- */
__global__ void __launch_bounds__(256, 1)
k_lstm(const int* __restrict__ x, const float* __restrict__ c0,
       const float* __restrict__ Whh1,
       const float* __restrict__ Wih2, const float* __restrict__ Whh2,
       const float* __restrict__ bih2, const float* __restrict__ bhh2,
       const float* __restrict__ Wfc, const float* __restrict__ bfc,
       float* __restrict__ out, char* __restrict__ ws)
{
  __shared__ float gates[64 * 17];     /* L2 gate exchange, padded stride */
  __shared__ f16 p1s[VOCn * 32];       /* L1 P1 slice [512 vocab][32 cols] */

  int* flags = (int*)(ws + WS_FLAGS);
  f16* h1b = (f16*)(ws + WS_H1);
  f16* h2b = (f16*)(ws + WS_H2);
  const f16* P1 = (const f16*)(ws + WS_P1);

  const int bid = blockIdx.x, tid = threadIdx.x;
  const int lane = tid & 63, wv = tid >> 6;
  const int cc = lane & 15, qq = lane >> 4;

  /* B-fragments (weights) live in registers for the whole kernel */
  half8 bfrA[2][16];
  float cst[4] = {0.f, 0.f, 0.f, 0.f};
  float bias0 = 0.f, bias1 = 0.f;
  int j0 = 0;

  if (bid < NL1) {
    /* layer-1: 8 hidden units, cols = [i x8][f x8] tile0, [g x8][o x8] tile1 */
    j0 = bid * 8;
    int g0 = (cc >> 3) * 512 + j0 + (cc & 7);
#pragma unroll
    for (int nt = 0; nt < 2; ++nt) {
      const float* wr = Whh1 + (g0 + nt * 1024) * HIDn;
#pragma unroll
      for (int ks = 0; ks < 16; ++ks) {
        const float* s = wr + ks * 32 + qq * 8;
        half8 hv;
#pragma unroll
        for (int j = 0; j < 8; ++j) hv[j] = (f16)s[j];
        bfrA[nt][ks] = hv;
      }
    }
    for (int i = tid; i < VOCn * 32; i += 256) {
      int v = i >> 5, n = i & 31;
      p1s[i] = P1[v * 2048 + (n >> 3) * 512 + j0 + (n & 7)];
    }
    if (cc < 8) {
#pragma unroll
      for (int r = 0; r < 4; ++r)
        cst[r] = c0[(wv * 16 + qq * 4 + r) * HIDn + j0 + cc];
    }
  } else if (bid < NL1 + NL2) {
    /* layer-2: 4 hidden units, cols = [i x4][f x4][g x4][o x4], K=1024 (h1|h2) */
    j0 = (bid - NL1) * 4;
    int gcol = (cc >> 2) * 512 + j0 + (cc & 3);
#pragma unroll
    for (int ks = 0; ks < 32; ++ks) {
      const float* s = (ks < 16) ? (Wih2 + gcol * HIDn + ks * 32 + qq * 8)
                                 : (Whh2 + gcol * HIDn + (ks - 16) * 32 + qq * 8);
      half8 hv;
#pragma unroll
      for (int j = 0; j < 8; ++j) hv[j] = (f16)s[j];
      bfrA[ks >> 4][ks & 15] = hv;
    }
    bias0 = bih2[gcol] + bhh2[gcol];
    cst[0] = c0[(tid >> 2) * HIDn + j0 + (tid & 3)];
  } else {
    /* FC: 32 vocab cols */
    j0 = (bid - NL1 - NL2) * 32;
#pragma unroll
    for (int nt = 0; nt < 2; ++nt) {
      const float* wr = Wfc + (j0 + nt * 16 + cc) * HIDn;
#pragma unroll
      for (int ks = 0; ks < 16; ++ks) {
        const float* s = wr + ks * 32 + qq * 8;
        half8 hv;
#pragma unroll
        for (int j = 0; j < 8; ++j) hv[j] = (f16)s[j];
        bfrA[nt][ks] = hv;
      }
    }
    bias0 = bfc[j0 + cc];
    bias1 = bfc[j0 + 16 + cc];
  }
  __syncthreads();

  for (int p = 1; p <= NPHASE; ++p) {
    if (bid < NL1) {
      if (p <= SEQn) {                       /* compute h1_p from h1_{p-1}, x_{p-1} */
        const f16* hp = h1b + ((p - 1) & 1) * (BATCHn * HIDn);
        f16* ho = h1b + (p & 1) * (BATCHn * HIDn);
        int mrow = wv * 16 + cc;
        half8 a[16];
#pragma unroll
        for (int ks = 0; ks < 16; ++ks)
          a[ks] = *(const half8*)(hp + mrow * HIDn + ks * 32 + qq * 8);
        f32x4 acc0, acc1;
#pragma unroll
        for (int r = 0; r < 4; ++r) {
          int xv = x[(p - 1) * 64 + wv * 16 + qq * 4 + r];
          acc0[r] = (float)p1s[xv * 32 + cc];
          acc1[r] = (float)p1s[xv * 32 + 16 + cc];
        }
#pragma unroll
        for (int ks = 0; ks < 16; ++ks) {
          acc0 = __builtin_amdgcn_mfma_f32_16x16x32_f16(a[ks], bfrA[0][ks], acc0, 0, 0, 0);
          acc1 = __builtin_amdgcn_mfma_f32_16x16x32_f16(a[ks], bfrA[1][ks], acc1, 0, 0, 0);
        }
        /* lane c<8 holds i (acc0) and g (acc1); f,o live at lane^8 */
#pragma unroll
        for (int r = 0; r < 4; ++r) {
          float fv = __shfl_xor(acc0[r], 8);
          float ov = __shfl_xor(acc1[r], 8);
          if (cc < 8) {
            float iv = sigm_(acc0[r]);
            float gv = tanh_(acc1[r]);
            float ff = sigm_(fv);
            float oo = sigm_(ov);
            float cn = ff * cst[r] + iv * gv;
            cst[r] = cn;
            float hh = oo * tanh_(cn);
            ho[(wv * 16 + qq * 4 + r) * HIDn + j0 + cc] = (f16)hh;
          }
        }
      }
    } else if (bid < NL1 + NL2) {
      if (p >= 2 && p <= SEQn + 1) {         /* compute h2_{p-1} from h1_{p-1}, h2_{p-2} */
        const f16* h1p = h1b + ((p - 1) & 1) * (BATCHn * HIDn);
        const f16* h2p = h2b + (p & 1) * (BATCHn * HIDn);
        f16* ho = h2b + ((p - 1) & 1) * (BATCHn * HIDn);
        int mrow = wv * 16 + cc;
        half8 a[32];
#pragma unroll
        for (int ks = 0; ks < 16; ++ks)
          a[ks] = *(const half8*)(h1p + mrow * HIDn + ks * 32 + qq * 8);
#pragma unroll
        for (int ks = 0; ks < 16; ++ks)
          a[16 + ks] = *(const half8*)(h2p + mrow * HIDn + ks * 32 + qq * 8);
        f32x4 acc;
#pragma unroll
        for (int r = 0; r < 4; ++r) acc[r] = bias0;
#pragma unroll
        for (int ks = 0; ks < 32; ++ks)
          acc = __builtin_amdgcn_mfma_f32_16x16x32_f16(a[ks], bfrA[ks >> 4][ks & 15], acc, 0, 0, 0);
#pragma unroll
        for (int r = 0; r < 4; ++r)
          gates[(wv * 16 + qq * 4 + r) * 17 + cc] = acc[r];
        __syncthreads();
        {
          int u = tid & 3, m = tid >> 2;
          float gi = gates[m * 17 + u];
          float gf = gates[m * 17 + 4 + u];
          float gg = gates[m * 17 + 8 + u];
          float go = gates[m * 17 + 12 + u];
          float cn = sigm_(gf) * cst[0] + sigm_(gi) * tanh_(gg);
          cst[0] = cn;
          float hh = sigm_(go) * tanh_(cn);
          ho[m * HIDn + j0 + u] = (f16)hh;
        }
      }
    } else {
      if (p >= 3) {                          /* out_{p-3} = h2_{p-2} @ WfcT + bfc */
        const f16* h2p = h2b + (p & 1) * (BATCHn * HIDn);
        float* op = out + (size_t)(p - 3) * (BATCHn * VOCn);
        int mrow = wv * 16 + cc;
        half8 a[16];
#pragma unroll
        for (int ks = 0; ks < 16; ++ks)
          a[ks] = *(const half8*)(h2p + mrow * HIDn + ks * 32 + qq * 8);
        f32x4 acc0, acc1;
#pragma unroll
        for (int r = 0; r < 4; ++r) { acc0[r] = bias0; acc1[r] = bias1; }
#pragma unroll
        for (int ks = 0; ks < 16; ++ks) {
          acc0 = __builtin_amdgcn_mfma_f32_16x16x32_f16(a[ks], bfrA[0][ks], acc0, 0, 0, 0);
          acc1 = __builtin_amdgcn_mfma_f32_16x16x32_f16(a[ks], bfrA[1][ks], acc1, 0, 0, 0);
        }
#pragma unroll
        for (int r = 0; r < 4; ++r) {
          int m = wv * 16 + qq * 4 + r;
          op[m * VOCn + j0 + cc] = acc0[r];
          op[m * VOCn + j0 + 16 + cc] = acc1[r];
        }
      }
    }

    /* ---- grid-wide phase barrier: release flag, all-poll-all, acquire ---- */
    __syncthreads();
    if (tid == 0)
      __hip_atomic_store(&flags[bid], p, __ATOMIC_RELEASE, __HIP_MEMORY_SCOPE_AGENT);
    if (tid < NBLK) {
      while (__hip_atomic_load(&flags[tid], __ATOMIC_RELAXED, __HIP_MEMORY_SCOPE_AGENT) < p)
        __builtin_amdgcn_s_sleep(1);
    }
    __threadfence();
    __syncthreads();
  }
}

extern "C" void kernel_launch(void* const* d_in, const int* in_sizes, int n_in,
                              void* d_out, int out_size, void* d_ws, size_t ws_size,
                              hipStream_t stream) {
  (void)in_sizes; (void)n_in; (void)out_size; (void)ws_size;
  const int*   x    = (const int*)  d_in[0];
  const float* h0   = (const float*)d_in[1];
  const float* c0   = (const float*)d_in[2];
  const float* emb  = (const float*)d_in[3];
  const float* Wih1 = (const float*)d_in[4];
  const float* Whh1 = (const float*)d_in[5];
  const float* bih1 = (const float*)d_in[6];
  const float* bhh1 = (const float*)d_in[7];
  const float* Wih2 = (const float*)d_in[8];
  const float* Whh2 = (const float*)d_in[9];
  const float* bih2 = (const float*)d_in[10];
  const float* bhh2 = (const float*)d_in[11];
  const float* Wfc  = (const float*)d_in[12];
  const float* bfc  = (const float*)d_in[13];
  char* ws = (char*)d_ws;

  hipLaunchKernelGGL(k_init, dim3(128), dim3(256), 0, stream, h0, ws);
  hipLaunchKernelGGL(k_p1,   dim3(512), dim3(256), 0, stream, emb, Wih1, bih1, bhh1, ws);
  hipLaunchKernelGGL(k_lstm, dim3(NBLK), dim3(256), 0, stream,
                     x, c0, Whh1, Wih2, Whh2, bih2, bhh2, Wfc, bfc,
                     (float*)d_out, ws);
}

// Round 2
// 20711.748 us; speedup vs baseline: 1.3212x; 1.3212x over previous
//
#include <hip/hip_runtime.h>

#define SEQn   1024
#define BATCHn 64
#define EMBn   256
#define HIDn   512
#define VOCn   512

#define NL1 64
#define NL2 128
#define NFC 16
#define NBLK (NL1 + NL2 + NFC)   /* 208 blocks, <= 256 CUs -> all co-resident */
#define NPHASE (SEQn + 2)        /* 1026 phases: skewed L1 / L2 / FC pipeline */

using f16   = _Float16;
using half8 = __attribute__((ext_vector_type(8))) _Float16;
using f32x4 = __attribute__((ext_vector_type(4))) float;

/* workspace layout (bytes) */
#define WS_FLAGS 0                                /* 256 ints              */
#define WS_H1    4096                             /* 2 x [64][512] f16     */
#define WS_H2    (WS_H1 + 2*BATCHn*HIDn*2)
#define WS_P1    (WS_H2 + 2*BATCHn*HIDn*2)        /* [512][2048] f16, 2MB  */

__device__ __forceinline__ float sigm_(float v) { return 1.0f / (1.0f + __expf(-v)); }
__device__ __forceinline__ float tanh_(float v) { return 1.0f - 2.0f / (__expf(2.0f * v) + 1.0f); }

/* ---- agent-scope (sc1) cache-bypass comm helpers: NO wbl2/inv fences ---- */
__device__ __forceinline__ unsigned ld_u32_agent(const unsigned* p) {
  return __hip_atomic_load(p, __ATOMIC_RELAXED, __HIP_MEMORY_SCOPE_AGENT);
}
__device__ __forceinline__ half8 ld_h8_agent(const f16* p) {
  union { half8 h; unsigned u[4]; } r;
  const unsigned* q = (const unsigned*)p;
  r.u[0] = ld_u32_agent(q + 0);
  r.u[1] = ld_u32_agent(q + 1);
  r.u[2] = ld_u32_agent(q + 2);
  r.u[3] = ld_u32_agent(q + 3);
  return r.h;
}
__device__ __forceinline__ void st_f16_agent(f16* p, float v) {
  f16 hv = (f16)v;
  unsigned short b = __builtin_bit_cast(unsigned short, hv);
  asm volatile("global_store_short %0, %1, off sc1" :: "v"(p), "v"(b) : "memory");
}

/* ---- init: zero barrier flags, seed h1/h2 ping-pong buffer 0 from h0 ---- */
__global__ void k_init(const float* __restrict__ h0, char* __restrict__ ws) {
  int i = blockIdx.x * 256 + threadIdx.x;          /* grid 128*256 = 32768 */
  f16* h1b = (f16*)(ws + WS_H1);
  f16* h2b = (f16*)(ws + WS_H2);
  float v = h0[i];
  h1b[i] = (f16)v;
  h2b[i] = (f16)v;
  if (i < 1024) ((int*)(ws + WS_FLAGS))[i] = 0;
}

/* ---- P1[v][g] = sum_e emb[v][e]*Wih1[g][e] + bih1[g] + bhh1[g] (fp16) ---- */
__global__ void k_p1(const float* __restrict__ emb, const float* __restrict__ Wih1,
                     const float* __restrict__ bih1, const float* __restrict__ bhh1,
                     char* __restrict__ ws) {
  __shared__ float elds[32 * 256];
  int tid = threadIdx.x;
  int vb = blockIdx.x >> 5, gb = blockIdx.x & 31;  /* grid 512 */
  for (int i = tid; i < 32 * 256; i += 256) elds[i] = emb[vb * 32 * 256 + i];
  __syncthreads();
  int gl = tid & 63, vs = tid >> 6;
  int g = gb * 64 + gl;
  float bias = bih1[g] + bhh1[g];
  float acc[8];
#pragma unroll
  for (int r = 0; r < 8; ++r) acc[r] = bias;
  const float* wrow = Wih1 + g * EMBn;
#pragma unroll 4
  for (int e = 0; e < EMBn; ++e) {
    float w = wrow[e];
#pragma unroll
    for (int r = 0; r < 8; ++r) acc[r] += elds[(vs * 8 + r) * 256 + e] * w;
  }
  f16* P1 = (f16*)(ws + WS_P1);
#pragma unroll
  for (int r = 0; r < 8; ++r) P1[(vb * 32 + vs * 8 + r) * 2048 + g] = (f16)acc[r];
}

/* ---- persistent skewed-pipeline kernel ---- */
__global__ void __launch_bounds__(256, 1)
k_lstm(const int* __restrict__ x, const float* __restrict__ c0,
       const float* __restrict__ Whh1,
       const float* __restrict__ Wih2, const float* __restrict__ Whh2,
       const float* __restrict__ bih2, const float* __restrict__ bhh2,
       const float* __restrict__ Wfc, const float* __restrict__ bfc,
       float* __restrict__ out, char* __restrict__ ws)
{
  __shared__ float gates[64 * 17];     /* L2 gate exchange, padded stride */
  __shared__ f16 p1s[VOCn * 32];       /* L1 P1 slice [512 vocab][32 cols] */

  int* flags = (int*)(ws + WS_FLAGS);
  f16* h1b = (f16*)(ws + WS_H1);
  f16* h2b = (f16*)(ws + WS_H2);
  const f16* P1 = (const f16*)(ws + WS_P1);

  const int bid = blockIdx.x, tid = threadIdx.x;
  const int lane = tid & 63, wv = tid >> 6;
  const int cc = lane & 15, qq = lane >> 4;

  /* B-fragments (weights) live in registers for the whole kernel */
  half8 bfrA[2][16];
  float cst[4] = {0.f, 0.f, 0.f, 0.f};
  float bias0 = 0.f, bias1 = 0.f;
  int j0 = 0;

  if (bid < NL1) {
    /* layer-1: 8 hidden units, cols = [i x8][f x8] tile0, [g x8][o x8] tile1 */
    j0 = bid * 8;
    int g0 = (cc >> 3) * 512 + j0 + (cc & 7);
#pragma unroll
    for (int nt = 0; nt < 2; ++nt) {
      const float* wr = Whh1 + (g0 + nt * 1024) * HIDn;
#pragma unroll
      for (int ks = 0; ks < 16; ++ks) {
        const float* s = wr + ks * 32 + qq * 8;
        half8 hv;
#pragma unroll
        for (int j = 0; j < 8; ++j) hv[j] = (f16)s[j];
        bfrA[nt][ks] = hv;
      }
    }
    for (int i = tid; i < VOCn * 32; i += 256) {
      int v = i >> 5, n = i & 31;
      p1s[i] = P1[v * 2048 + (n >> 3) * 512 + j0 + (n & 7)];
    }
    if (cc < 8) {
#pragma unroll
      for (int r = 0; r < 4; ++r)
        cst[r] = c0[(wv * 16 + qq * 4 + r) * HIDn + j0 + cc];
    }
  } else if (bid < NL1 + NL2) {
    /* layer-2: 4 hidden units, cols = [i x4][f x4][g x4][o x4], K=1024 (h1|h2) */
    j0 = (bid - NL1) * 4;
    int gcol = (cc >> 2) * 512 + j0 + (cc & 3);
#pragma unroll
    for (int ks = 0; ks < 32; ++ks) {
      const float* s = (ks < 16) ? (Wih2 + gcol * HIDn + ks * 32 + qq * 8)
                                 : (Whh2 + gcol * HIDn + (ks - 16) * 32 + qq * 8);
      half8 hv;
#pragma unroll
      for (int j = 0; j < 8; ++j) hv[j] = (f16)s[j];
      bfrA[ks >> 4][ks & 15] = hv;
    }
    bias0 = bih2[gcol] + bhh2[gcol];
    cst[0] = c0[(tid >> 2) * HIDn + j0 + (tid & 3)];
  } else {
    /* FC: 32 vocab cols */
    j0 = (bid - NL1 - NL2) * 32;
#pragma unroll
    for (int nt = 0; nt < 2; ++nt) {
      const float* wr = Wfc + (j0 + nt * 16 + cc) * HIDn;
#pragma unroll
      for (int ks = 0; ks < 16; ++ks) {
        const float* s = wr + ks * 32 + qq * 8;
        half8 hv;
#pragma unroll
        for (int j = 0; j < 8; ++j) hv[j] = (f16)s[j];
        bfrA[nt][ks] = hv;
      }
    }
    bias0 = bfc[j0 + cc];
    bias1 = bfc[j0 + 16 + cc];
  }
  __syncthreads();

  for (int p = 1; p <= NPHASE; ++p) {
    if (bid < NL1) {
      if (p <= SEQn) {                       /* compute h1_p from h1_{p-1}, x_{p-1} */
        const f16* hp = h1b + ((p - 1) & 1) * (BATCHn * HIDn);
        f16* ho = h1b + (p & 1) * (BATCHn * HIDn);
        int mrow = wv * 16 + cc;
        half8 a[16];
#pragma unroll
        for (int ks = 0; ks < 16; ++ks)
          a[ks] = ld_h8_agent(hp + mrow * HIDn + ks * 32 + qq * 8);
        f32x4 acc0, acc1;
#pragma unroll
        for (int r = 0; r < 4; ++r) {
          int xv = x[(p - 1) * 64 + wv * 16 + qq * 4 + r];
          acc0[r] = (float)p1s[xv * 32 + cc];
          acc1[r] = (float)p1s[xv * 32 + 16 + cc];
        }
#pragma unroll
        for (int ks = 0; ks < 16; ++ks) {
          acc0 = __builtin_amdgcn_mfma_f32_16x16x32_f16(a[ks], bfrA[0][ks], acc0, 0, 0, 0);
          acc1 = __builtin_amdgcn_mfma_f32_16x16x32_f16(a[ks], bfrA[1][ks], acc1, 0, 0, 0);
        }
        /* lane c<8 holds i (acc0) and g (acc1); f,o live at lane^8 */
#pragma unroll
        for (int r = 0; r < 4; ++r) {
          float fv = __shfl_xor(acc0[r], 8);
          float ov = __shfl_xor(acc1[r], 8);
          if (cc < 8) {
            float iv = sigm_(acc0[r]);
            float gv = tanh_(acc1[r]);
            float ff = sigm_(fv);
            float oo = sigm_(ov);
            float cn = ff * cst[r] + iv * gv;
            cst[r] = cn;
            float hh = oo * tanh_(cn);
            st_f16_agent(ho + (wv * 16 + qq * 4 + r) * HIDn + j0 + cc, hh);
          }
        }
      }
    } else if (bid < NL1 + NL2) {
      if (p >= 2 && p <= SEQn + 1) {         /* compute h2_{p-1} from h1_{p-1}, h2_{p-2} */
        const f16* h1p = h1b + ((p - 1) & 1) * (BATCHn * HIDn);
        const f16* h2p = h2b + (p & 1) * (BATCHn * HIDn);
        f16* ho = h2b + ((p - 1) & 1) * (BATCHn * HIDn);
        int mrow = wv * 16 + cc;
        half8 a[32];
#pragma unroll
        for (int ks = 0; ks < 16; ++ks)
          a[ks] = ld_h8_agent(h1p + mrow * HIDn + ks * 32 + qq * 8);
#pragma unroll
        for (int ks = 0; ks < 16; ++ks)
          a[16 + ks] = ld_h8_agent(h2p + mrow * HIDn + ks * 32 + qq * 8);
        f32x4 acc;
#pragma unroll
        for (int r = 0; r < 4; ++r) acc[r] = bias0;
#pragma unroll
        for (int ks = 0; ks < 32; ++ks)
          acc = __builtin_amdgcn_mfma_f32_16x16x32_f16(a[ks], bfrA[ks >> 4][ks & 15], acc, 0, 0, 0);
#pragma unroll
        for (int r = 0; r < 4; ++r)
          gates[(wv * 16 + qq * 4 + r) * 17 + cc] = acc[r];
        __syncthreads();
        {
          int u = tid & 3, m = tid >> 2;
          float gi = gates[m * 17 + u];
          float gf = gates[m * 17 + 4 + u];
          float gg = gates[m * 17 + 8 + u];
          float go = gates[m * 17 + 12 + u];
          float cn = sigm_(gf) * cst[0] + sigm_(gi) * tanh_(gg);
          cst[0] = cn;
          float hh = sigm_(go) * tanh_(cn);
          st_f16_agent(ho + m * HIDn + j0 + u, hh);
        }
      }
    } else {
      if (p >= 3) {                          /* out_{p-3} = h2_{p-2} @ WfcT + bfc */
        const f16* h2p = h2b + (p & 1) * (BATCHn * HIDn);
        float* op = out + (size_t)(p - 3) * (BATCHn * VOCn);
        int mrow = wv * 16 + cc;
        half8 a[16];
#pragma unroll
        for (int ks = 0; ks < 16; ++ks)
          a[ks] = ld_h8_agent(h2p + mrow * HIDn + ks * 32 + qq * 8);
        f32x4 acc0, acc1;
#pragma unroll
        for (int r = 0; r < 4; ++r) { acc0[r] = bias0; acc1[r] = bias1; }
#pragma unroll
        for (int ks = 0; ks < 16; ++ks) {
          acc0 = __builtin_amdgcn_mfma_f32_16x16x32_f16(a[ks], bfrA[0][ks], acc0, 0, 0, 0);
          acc1 = __builtin_amdgcn_mfma_f32_16x16x32_f16(a[ks], bfrA[1][ks], acc1, 0, 0, 0);
        }
        /* nontemporal: keep L2 clean of streaming output */
#pragma unroll
        for (int r = 0; r < 4; ++r) {
          int m = wv * 16 + qq * 4 + r;
          __builtin_nontemporal_store(acc0[r], &op[m * VOCn + j0 + cc]);
          __builtin_nontemporal_store(acc1[r], &op[m * VOCn + j0 + 16 + cc]);
        }
      }
    }

    /* ---- grid-wide phase barrier, fence-free:
       every wave drains its own sc1 stores (ack at coherence point), block
       joins, then one relaxed flag store; consumers poll relaxed sc1 loads.
       No buffer_wbl2 / buffer_inv anywhere in the loop. ---- */
    asm volatile("s_waitcnt vmcnt(0)" ::: "memory");
    __syncthreads();
    if (tid == 0)
      __hip_atomic_store(&flags[bid], p, __ATOMIC_RELAXED, __HIP_MEMORY_SCOPE_AGENT);
    if (tid < NBLK) {
      while (__hip_atomic_load(&flags[tid], __ATOMIC_RELAXED, __HIP_MEMORY_SCOPE_AGENT) < p)
        __builtin_amdgcn_s_sleep(1);
    }
    __syncthreads();
  }
}

extern "C" void kernel_launch(void* const* d_in, const int* in_sizes, int n_in,
                              void* d_out, int out_size, void* d_ws, size_t ws_size,
                              hipStream_t stream) {
  (void)in_sizes; (void)n_in; (void)out_size; (void)ws_size;
  const int*   x    = (const int*)  d_in[0];
  const float* h0   = (const float*)d_in[1];
  const float* c0   = (const float*)d_in[2];
  const float* emb  = (const float*)d_in[3];
  const float* Wih1 = (const float*)d_in[4];
  const float* Whh1 = (const float*)d_in[5];
  const float* bih1 = (const float*)d_in[6];
  const float* bhh1 = (const float*)d_in[7];
  const float* Wih2 = (const float*)d_in[8];
  const float* Whh2 = (const float*)d_in[9];
  const float* bih2 = (const float*)d_in[10];
  const float* bhh2 = (const float*)d_in[11];
  const float* Wfc  = (const float*)d_in[12];
  const float* bfc  = (const float*)d_in[13];
  char* ws = (char*)d_ws;

  hipLaunchKernelGGL(k_init, dim3(128), dim3(256), 0, stream, h0, ws);
  hipLaunchKernelGGL(k_p1,   dim3(512), dim3(256), 0, stream, emb, Wih1, bih1, bhh1, ws);
  hipLaunchKernelGGL(k_lstm, dim3(NBLK), dim3(256), 0, stream,
                     x, c0, Whh1, Wih2, Whh2, bih2, bhh2, Wfc, bfc,
                     (float*)d_out, ws);
}

// Round 3
// 12761.496 us; speedup vs baseline: 2.1444x; 1.6230x over previous
//
#include <hip/hip_runtime.h>

#define SEQn   1024
#define BATCHn 64
#define EMBn   256
#define HIDn   512
#define VOCn   512

#define NL1 64
#define NL2 64
#define NFC 16
#define NBLK (NL1 + NL2 + NFC)   /* 144 blocks, <= 256 CUs -> all co-resident */
#define NPHASE (SEQn + 2)        /* 1026 phases: skewed L1 / L2 / FC pipeline */
#define HBUF (BATCHn * HIDn)     /* 32768 f16 = 64KB */

using f16   = _Float16;
using half8 = __attribute__((ext_vector_type(8))) _Float16;
using f32x4 = __attribute__((ext_vector_type(4))) float;

/* workspace layout (bytes) */
#define WS_CNT 0                            /* 16 phase slots x 128B     */
#define WS_H1  4096                         /* 4 rep x 2 par x 64KB      */
#define WS_H2  (WS_H1 + 8 * HBUF * 2)
#define WS_P1  (WS_H2 + 8 * HBUF * 2)       /* [512][2048] f16, 2MB      */

__device__ __forceinline__ float sigm_(float v) { return 1.0f / (1.0f + __expf(-v)); }
__device__ __forceinline__ float tanh_(float v) { return 1.0f - 2.0f / (__expf(2.0f * v) + 1.0f); }

/* agent-scope (MALL coherence point) comm helpers — no wbl2/inv fences */
__device__ __forceinline__ half8 ld_h8_sc1(const f16* p) {
  union { half8 h; unsigned long long u[2]; } r;
  const unsigned long long* q = (const unsigned long long*)p;
  r.u[0] = __hip_atomic_load(q + 0, __ATOMIC_RELAXED, __HIP_MEMORY_SCOPE_AGENT);
  r.u[1] = __hip_atomic_load(q + 1, __ATOMIC_RELAXED, __HIP_MEMORY_SCOPE_AGENT);
  return r.h;
}
__device__ __forceinline__ void st_u32_sc1(f16* p, unsigned v) {
  asm volatile("global_store_dword %0, %1, off sc1" :: "v"(p), "v"(v) : "memory");
}
__device__ __forceinline__ unsigned pack2(float a, float b) {
  f16 lo = (f16)a, hi = (f16)b;
  return (unsigned)__builtin_bit_cast(unsigned short, lo)
       | ((unsigned)__builtin_bit_cast(unsigned short, hi) << 16);
}

/* ---- init: zero counters, seed all h1/h2 replicas (parity 0) from h0 ---- */
__global__ void k_init(const float* __restrict__ h0, char* __restrict__ ws) {
  int i = blockIdx.x * 256 + threadIdx.x;          /* grid 1024*256 = 262144 */
  f16* h1b = (f16*)(ws + WS_H1);
  f16* h2b = (f16*)(ws + WS_H2);
  float v = h0[i & (HBUF - 1)];
  h1b[i] = (f16)v;
  h2b[i] = (f16)v;
  if (i < 1024) ((int*)ws)[i] = 0;
}

/* ---- P1[v][g] = emb[v] . Wih1[g] + bih1[g] + bhh1[g]  (fp16) ---- */
__global__ void k_p1(const float* __restrict__ emb, const float* __restrict__ Wih1,
                     const float* __restrict__ bih1, const float* __restrict__ bhh1,
                     char* __restrict__ ws) {
  __shared__ float elds[32 * 256];
  int tid = threadIdx.x;
  int vb = blockIdx.x >> 5, gb = blockIdx.x & 31;  /* grid 512 */
  for (int i = tid; i < 32 * 256; i += 256) elds[i] = emb[vb * 32 * 256 + i];
  __syncthreads();
  int gl = tid & 63, vs = tid >> 6;
  int g = gb * 64 + gl;
  float bias = bih1[g] + bhh1[g];
  float acc[8];
#pragma unroll
  for (int r = 0; r < 8; ++r) acc[r] = bias;
  const float* wrow = Wih1 + g * EMBn;
#pragma unroll 4
  for (int e = 0; e < EMBn; ++e) {
    float w = wrow[e];
#pragma unroll
    for (int r = 0; r < 8; ++r) acc[r] += elds[(vs * 8 + r) * 256 + e] * w;
  }
  f16* P1 = (f16*)(ws + WS_P1);
#pragma unroll
  for (int r = 0; r < 8; ++r) P1[(vb * 32 + vs * 8 + r) * 2048 + g] = (f16)acc[r];
}

/* ---- persistent skewed-pipeline kernel ---- */
__global__ void __launch_bounds__(256, 1)
k_lstm(const int* __restrict__ x, const float* __restrict__ c0,
       const float* __restrict__ Whh1,
       const float* __restrict__ Wih2, const float* __restrict__ Whh2,
       const float* __restrict__ bih2, const float* __restrict__ bhh2,
       const float* __restrict__ Wfc, const float* __restrict__ bfc,
       float* __restrict__ out, char* __restrict__ ws)
{
  __shared__ float part[2][64][33];    /* L2 partial gates: [K-half][row][col] */
  __shared__ f16 p1s[VOCn * 32];       /* L1 P1 slice [512 vocab][32 cols]     */

  f16* h1base = (f16*)(ws + WS_H1);
  f16* h2base = (f16*)(ws + WS_H2);
  const f16* P1 = (const f16*)(ws + WS_P1);

  const int bid = blockIdx.x, tid = threadIdx.x;
  const int lane = tid & 63, wv = tid >> 6;
  const int cc = lane & 15, qq = lane >> 4;
  const int rep = bid & 3;             /* which h replica this block reads */

  half8 bfrA[2][16];                   /* weight B-fragments, resident all run */
  float cst[4] = {0.f, 0.f, 0.f, 0.f};
  float bias0 = 0.f, bias1 = 0.f;
  int j0 = 0;
  /* L2 wave roles */
  const int khalf = wv >> 1;           /* 0: h1/Wih2, 1: h2/Whh2 */
  const int mh = wv & 1;               /* M 32-row half */

  if (bid < NL1) {
    /* layer-1: 8 units; cols = [i x8][f x8] tile0, [g x8][o x8] tile1 */
    j0 = bid * 8;
    int g0 = (cc >> 3) * 512 + j0 + (cc & 7);
#pragma unroll
    for (int nt = 0; nt < 2; ++nt) {
      const float* wr = Whh1 + (g0 + nt * 1024) * HIDn;
#pragma unroll
      for (int ks = 0; ks < 16; ++ks) {
        const float* s = wr + ks * 32 + qq * 8;
        half8 hv;
#pragma unroll
        for (int j = 0; j < 8; ++j) hv[j] = (f16)s[j];
        bfrA[nt][ks] = hv;
      }
    }
    for (int i = tid; i < VOCn * 32; i += 256) {
      int v = i >> 5, n = i & 31;
      p1s[i] = P1[v * 2048 + (n >> 3) * 512 + j0 + (n & 7)];
    }
    if (cc < 8) {
#pragma unroll
      for (int r = 0; r < 4; ++r)
        cst[r] = c0[(wv * 16 + qq * 4 + r) * HIDn + j0 + cc];
    }
  } else if (bid < NL1 + NL2) {
    /* layer-2: 8 units; waves split (K-half x M-half); cols as L1 */
    j0 = (bid - NL1) * 8;
    int g0 = (cc >> 3) * 512 + j0 + (cc & 7);
    const float* W = khalf ? Whh2 : Wih2;
#pragma unroll
    for (int nt = 0; nt < 2; ++nt) {
      const float* wr = W + (g0 + nt * 1024) * HIDn;
#pragma unroll
      for (int ks = 0; ks < 16; ++ks) {
        const float* s = wr + ks * 32 + qq * 8;
        half8 hv;
#pragma unroll
        for (int j = 0; j < 8; ++j) hv[j] = (f16)s[j];
        bfrA[nt][ks] = hv;
      }
    }
    if (khalf == 0) {
      int gc0 = g0, gc1 = g0 + 1024;
      bias0 = bih2[gc0] + bhh2[gc0];
      bias1 = bih2[gc1] + bhh2[gc1];
    }
    /* epilogue cell state: thread owns (m = tid>>2, units 2u, 2u+1) */
    {
      int m = tid >> 2, u = tid & 3;
      cst[0] = c0[m * HIDn + j0 + 2 * u];
      cst[1] = c0[m * HIDn + j0 + 2 * u + 1];
    }
  } else {
    /* FC: 32 vocab cols */
    j0 = (bid - NL1 - NL2) * 32;
#pragma unroll
    for (int nt = 0; nt < 2; ++nt) {
      const float* wr = Wfc + (j0 + nt * 16 + cc) * HIDn;
#pragma unroll
      for (int ks = 0; ks < 16; ++ks) {
        const float* s = wr + ks * 32 + qq * 8;
        half8 hv;
#pragma unroll
        for (int j = 0; j < 8; ++j) hv[j] = (f16)s[j];
        bfrA[nt][ks] = hv;
      }
    }
    bias0 = bfc[j0 + cc];
    bias1 = bfc[j0 + 16 + cc];
  }
  __syncthreads();

  for (int p = 1; p <= NPHASE; ++p) {
    if (bid < NL1) {
      if (p <= SEQn) {                 /* h1_p = f(h1_{p-1}, x_{p-1}) */
        const f16* hp = h1base + (rep * 2 + ((p - 1) & 1)) * HBUF;
        int mrow = wv * 16 + cc;
        half8 a[16];
#pragma unroll
        for (int ks = 0; ks < 16; ++ks)
          a[ks] = ld_h8_sc1(hp + mrow * HIDn + ks * 32 + qq * 8);
        f32x4 acc0, acc1;
#pragma unroll
        for (int r = 0; r < 4; ++r) {
          int xv = x[(p - 1) * 64 + wv * 16 + qq * 4 + r];
          acc0[r] = (float)p1s[xv * 32 + cc];
          acc1[r] = (float)p1s[xv * 32 + 16 + cc];
        }
#pragma unroll
        for (int ks = 0; ks < 16; ++ks) {
          acc0 = __builtin_amdgcn_mfma_f32_16x16x32_f16(a[ks], bfrA[0][ks], acc0, 0, 0, 0);
          acc1 = __builtin_amdgcn_mfma_f32_16x16x32_f16(a[ks], bfrA[1][ks], acc1, 0, 0, 0);
        }
        float hv4[4];
#pragma unroll
        for (int r = 0; r < 4; ++r) {
          float fv = __shfl_xor(acc0[r], 8);
          float ov = __shfl_xor(acc1[r], 8);
          float iv = sigm_(acc0[r]);
          float gv = tanh_(acc1[r]);
          float ff = sigm_(fv);
          float oo = sigm_(ov);
          float cn = ff * cst[r] + iv * gv;
          cst[r] = cn;                 /* garbage for cc>=8, never consumed */
          hv4[r] = oo * tanh_(cn);
        }
#pragma unroll
        for (int r = 0; r < 4; ++r) {
          float other = __shfl_xor(hv4[r], 1);
          if ((cc & 1) == 0 && cc < 8) {
            unsigned u32 = pack2(hv4[r], other);
            int off = (wv * 16 + qq * 4 + r) * HIDn + j0 + cc;
#pragma unroll
            for (int rp = 0; rp < 4; ++rp)
              st_u32_sc1(h1base + (rp * 2 + (p & 1)) * HBUF + off, u32);
          }
        }
      }
    } else if (bid < NL1 + NL2) {
      if (p >= 2 && p <= SEQn + 1) {   /* h2_{p-1} = f(h1_{p-1}, h2_{p-2}) */
        const f16* src = (khalf == 0)
            ? h1base + (rep * 2 + ((p - 1) & 1)) * HBUF
            : h2base + (rep * 2 + (p & 1)) * HBUF;
        f32x4 acc[2][2];
#pragma unroll
        for (int mt = 0; mt < 2; ++mt)
#pragma unroll
          for (int r = 0; r < 4; ++r) {
            acc[mt][0][r] = (khalf == 0) ? bias0 : 0.f;
            acc[mt][1][r] = (khalf == 0) ? bias1 : 0.f;
          }
#pragma unroll
        for (int mt = 0; mt < 2; ++mt) {
          int mrow = mh * 32 + mt * 16 + cc;
          half8 a[16];
#pragma unroll
          for (int ks = 0; ks < 16; ++ks)
            a[ks] = ld_h8_sc1(src + mrow * HIDn + ks * 32 + qq * 8);
#pragma unroll
          for (int ks = 0; ks < 16; ++ks) {
            acc[mt][0] = __builtin_amdgcn_mfma_f32_16x16x32_f16(a[ks], bfrA[0][ks], acc[mt][0], 0, 0, 0);
            acc[mt][1] = __builtin_amdgcn_mfma_f32_16x16x32_f16(a[ks], bfrA[1][ks], acc[mt][1], 0, 0, 0);
          }
        }
#pragma unroll
        for (int mt = 0; mt < 2; ++mt)
#pragma unroll
          for (int nt = 0; nt < 2; ++nt)
#pragma unroll
            for (int r = 0; r < 4; ++r)
              part[khalf][mh * 32 + mt * 16 + qq * 4 + r][nt * 16 + cc] = acc[mt][nt][r];
        __syncthreads();
        {
          int m = tid >> 2, u = tid & 3;
          f16* ho = h2base + ((p - 1) & 1) * HBUF;  /* + rep offset below */
          float hh[2];
#pragma unroll
          for (int w2 = 0; w2 < 2; ++w2) {
            int w = 2 * u + w2;
            float gi = part[0][m][w]      + part[1][m][w];
            float gf = part[0][m][8 + w]  + part[1][m][8 + w];
            float gg = part[0][m][16 + w] + part[1][m][16 + w];
            float go = part[0][m][24 + w] + part[1][m][24 + w];
            float cn = sigm_(gf) * cst[w2] + sigm_(gi) * tanh_(gg);
            cst[w2] = cn;
            hh[w2] = sigm_(go) * tanh_(cn);
          }
          unsigned u32 = pack2(hh[0], hh[1]);
          int off = m * HIDn + j0 + 2 * u;
#pragma unroll
          for (int rp = 0; rp < 4; ++rp)
            st_u32_sc1(ho + rp * 2 * HBUF + off, u32);
        }
      }
    } else {
      if (p >= 3) {                    /* out_{p-3} = h2_{p-2} @ WfcT + bfc */
        const f16* h2p = h2base + (rep * 2 + (p & 1)) * HBUF;
        float* op = out + (size_t)(p - 3) * (BATCHn * VOCn);
        int mrow = wv * 16 + cc;
        half8 a[16];
#pragma unroll
        for (int ks = 0; ks < 16; ++ks)
          a[ks] = ld_h8_sc1(h2p + mrow * HIDn + ks * 32 + qq * 8);
        f32x4 acc0, acc1;
#pragma unroll
        for (int r = 0; r < 4; ++r) { acc0[r] = bias0; acc1[r] = bias1; }
#pragma unroll
        for (int ks = 0; ks < 16; ++ks) {
          acc0 = __builtin_amdgcn_mfma_f32_16x16x32_f16(a[ks], bfrA[0][ks], acc0, 0, 0, 0);
          acc1 = __builtin_amdgcn_mfma_f32_16x16x32_f16(a[ks], bfrA[1][ks], acc1, 0, 0, 0);
        }
#pragma unroll
        for (int r = 0; r < 4; ++r) {
          int m = wv * 16 + qq * 4 + r;
          __builtin_nontemporal_store(acc0[r], &op[m * VOCn + j0 + cc]);
          __builtin_nontemporal_store(acc1[r], &op[m * VOCn + j0 + 16 + cc]);
        }
      }
    }

    /* ---- phase barrier: counter arrivals + single-line lazy poll ----
       producers drain sc1 h-stores to the MALL first (store-at-coherence-
       point replaces a release fence); FC skips the drain (out stores are
       fire-and-forget). Only tid 0 polls: one line, ~2 reqs/us per block. */
    if (bid < NL1 + NL2) asm volatile("s_waitcnt vmcnt(0)" ::: "memory");
    __syncthreads();
    if (tid == 0) {
      unsigned* cnt = (unsigned*)(ws + ((p & 15) * 128));
      __hip_atomic_fetch_add(cnt, 1u, __ATOMIC_RELAXED, __HIP_MEMORY_SCOPE_AGENT);
      while (__hip_atomic_load(cnt, __ATOMIC_RELAXED, __HIP_MEMORY_SCOPE_AGENT) < NBLK)
        __builtin_amdgcn_s_sleep(8);
      if (bid == 0)
        __hip_atomic_store((unsigned*)(ws + (((p + 8) & 15) * 128)), 0u,
                           __ATOMIC_RELAXED, __HIP_MEMORY_SCOPE_AGENT);
    }
    __syncthreads();
  }
}

extern "C" void kernel_launch(void* const* d_in, const int* in_sizes, int n_in,
                              void* d_out, int out_size, void* d_ws, size_t ws_size,
                              hipStream_t stream) {
  (void)in_sizes; (void)n_in; (void)out_size; (void)ws_size;
  const int*   x    = (const int*)  d_in[0];
  const float* h0   = (const float*)d_in[1];
  const float* c0   = (const float*)d_in[2];
  const float* emb  = (const float*)d_in[3];
  const float* Wih1 = (const float*)d_in[4];
  const float* Whh1 = (const float*)d_in[5];
  const float* bih1 = (const float*)d_in[6];
  const float* bhh1 = (const float*)d_in[7];
  const float* Wih2 = (const float*)d_in[8];
  const float* Whh2 = (const float*)d_in[9];
  const float* bih2 = (const float*)d_in[10];
  const float* bhh2 = (const float*)d_in[11];
  const float* Wfc  = (const float*)d_in[12];
  const float* bfc  = (const float*)d_in[13];
  char* ws = (char*)d_ws;

  hipLaunchKernelGGL(k_init, dim3(1024), dim3(256), 0, stream, h0, ws);
  hipLaunchKernelGGL(k_p1,   dim3(512), dim3(256), 0, stream, emb, Wih1, bih1, bhh1, ws);
  hipLaunchKernelGGL(k_lstm, dim3(NBLK), dim3(256), 0, stream,
                     x, c0, Whh1, Wih2, Whh2, bih2, bhh2, Wfc, bfc,
                     (float*)d_out, ws);
}